// Round 1
// baseline (1533.133 us; speedup 1.0000x reference)
//
#include <hip/hip_runtime.h>
#include <math.h>

#define NTOK 16384
#define HDIM 2048
#define KNOI 25
#define RPW  4            // rows per wave
#define WPB  4            // waves per block (256 threads) -> 16 rows/block
#define CHUNK 256         // floats of H per chunk (1 float4 per lane)
#define NCHUNK (HDIM / CHUNK)   // 8

// No LDS, no barriers. The 25 noise rows (200 KB total, 25.6 KB per chunk)
// are L1/L2-resident; each wave reads its float4 slice directly (coalesced
// 1 KB per (k,chunk)). RPW=4 amortizes the noise sweep over 4 rows, keeping
// total noise L2 traffic at ~0.82 GB (~2 TB/s per XCD, under the ~4.3 ceiling).
// VGPR ~150 -> launch_bounds(256,3): 3 waves/SIMD, 12 waves/CU; 12x8KB HBM
// loads in flight/CU saturates the input+target stream without prefetch.
__global__ __launch_bounds__(256, 3) void nce_main(
    const float* __restrict__ input,
    const float* __restrict__ weight,
    const float* __restrict__ bias,
    const float* __restrict__ uni,
    const int* __restrict__ target,
    const int* __restrict__ noise,
    float* __restrict__ out)
{
    float* pmt = out;
    float* pnt = out + NTOK;
    float* pmn = out + 2 * NTOK;
    float* pnn = out + 2 * NTOK + NTOK * KNOI;

    const int lane = threadIdx.x & 63;
    const int wave = threadIdx.x >> 6;
    int row0 = (blockIdx.x * WPB + wave) * RPW;
    row0 = __builtin_amdgcn_readfirstlane(row0);   // wave-uniform -> SGPR

    // Uniform byte offsets (SGPRs).
    unsigned noffb[KNOI];
#pragma unroll
    for (int k = 0; k < KNOI; ++k)
        noffb[k] = (unsigned)noise[k] * (unsigned)(HDIM * 4);

    unsigned toffb[RPW], ioffb[RPW];
#pragma unroll
    for (int r = 0; r < RPW; ++r) {
        toffb[r] = (unsigned)target[row0 + r] * (unsigned)(HDIM * 4);
        ioffb[r] = (unsigned)(row0 + r) * (unsigned)(HDIM * 4);
    }

    const char* wb = (const char*)weight;
    const char* ib = (const char*)input;
    const unsigned laneoff = (unsigned)lane * 16u;

    float acc[RPW][KNOI];
    float acct[RPW];
#pragma unroll
    for (int r = 0; r < RPW; ++r) {
        acct[r] = 0.f;
#pragma unroll
        for (int k = 0; k < KNOI; ++k) acc[r][k] = 0.f;
    }

#pragma unroll 1   // keep VGPR pressure flat; TLP hides per-chunk latency
    for (int c = 0; c < NCHUNK; ++c) {
        const unsigned cb = (unsigned)c * (unsigned)(CHUNK * 4) + laneoff;

        float4 inv[RPW], tgv[RPW];
#pragma unroll
        for (int r = 0; r < RPW; ++r) {
            inv[r] = *(const float4*)(ib + ioffb[r] + cb);   // HBM stream
            tgv[r] = *(const float4*)(wb + toffb[r] + cb);   // HBM gather
        }

#pragma unroll
        for (int k = 0; k < KNOI; ++k) {
            const float4 w = *(const float4*)(wb + noffb[k] + cb);  // L1/L2 hit
#pragma unroll
            for (int r = 0; r < RPW; ++r)
                acc[r][k] += inv[r].x * w.x + inv[r].y * w.y
                           + inv[r].z * w.z + inv[r].w * w.w;
        }
#pragma unroll
        for (int r = 0; r < RPW; ++r)
            acct[r] += inv[r].x * tgv[r].x + inv[r].y * tgv[r].y
                     + inv[r].z * tgv[r].z + inv[r].w * tgv[r].w;
    }

    // Pack-halving multi-value wave reduction: 32 slots (25 noise + target +
    // 6 zero pads) reduced in 5 pairing steps + 1 butterfly. Each step halves
    // both the value count and the lane-group size: ~32 shuffles/row vs 156
    // for per-value butterfly. Final: lane L holds total of value
    // m = bits(L5,L4,L3,L2,L1) -> (m0..m4); even lane of each pair stores.
    const int m = ((lane >> 5) & 1) | (((lane >> 4) & 1) << 1)
                | (((lane >> 3) & 1) << 2) | (((lane >> 2) & 1) << 3)
                | (((lane >> 1) & 1) << 4);

#pragma unroll
    for (int r = 0; r < RPW; ++r) {
        float v[32];   // fully unrolled -> stays in registers
#pragma unroll
        for (int k = 0; k < KNOI; ++k) v[k] = acc[r][k];
        v[KNOI] = acct[r];
#pragma unroll
        for (int j = KNOI + 1; j < 32; ++j) v[j] = 0.f;

#pragma unroll
        for (int s = 0; s < 5; ++s) {
            const int h  = 32 >> s;   // lane bit / shfl mask: 32,16,8,4,2
            const int np = 16 >> s;   // pairs this step
#pragma unroll
            for (int i = 0; i < np; ++i) {
                const float lo = v[2 * i], hi = v[2 * i + 1];
                const bool up = (lane & h) != 0;
                const float send = up ? lo : hi;
                const float recv = __shfl_xor(send, h, 64);
                v[i] = (up ? hi : lo) + recv;
            }
        }
        const float tot = v[0] + __shfl_xor(v[0], 1, 64);

        if ((lane & 1) == 0) {
            const int row = row0 + r;
            if (m < KNOI) {
                const int nk = noise[m];                     // L2-hot gathers
                pmn[row * KNOI + m] = expf(tot + bias[nk]);
                pnn[row * KNOI + m] = uni[nk];
            } else if (m == KNOI) {
                const int tk = (int)(toffb[r] >> 13);        // off = idx*8192
                pmt[row] = expf(tot + bias[tk]);
                pnt[row] = uni[tk];
            }
        }
    }
}

extern "C" void kernel_launch(void* const* d_in, const int* in_sizes, int n_in,
                              void* d_out, int out_size, void* d_ws, size_t ws_size,
                              hipStream_t stream) {
    const float* input  = (const float*)d_in[0];
    const float* weight = (const float*)d_in[1];
    const float* bias   = (const float*)d_in[2];
    const float* uni    = (const float*)d_in[3];
    const int*   target = (const int*)d_in[4];
    const int*   noise  = (const int*)d_in[5];
    float* out = (float*)d_out;

    const dim3 grid(NTOK / (WPB * RPW));   // 1024 blocks x 16 rows
    const dim3 block(256);
    hipLaunchKernelGGL(nce_main, grid, block, 0, stream,
                       input, weight, bias, uni, target, noise, out);
}

// Round 2
// 582.492 us; speedup vs baseline: 2.6320x; 2.6320x over previous
//
#include <hip/hip_runtime.h>
#include <math.h>

#define NTOK 16384
#define HDIM 2048
#define KNOI 25
#define RPW  2            // rows per wave
#define WPB  4            // waves per block (256 threads)
#define CHUNK 256         // floats of H per chunk
#define NCHUNK (HDIM / CHUNK)   // 8

typedef __attribute__((address_space(3))) unsigned lds_uint;
typedef __attribute__((address_space(1))) const unsigned glob_uint;

// Async global->LDS, 16B per lane, dest = uniform base + lane*16 (HW rule).
__device__ __forceinline__ void stage16(const void* g, void* l) {
    __builtin_amdgcn_global_load_lds((glob_uint*)g, (lds_uint*)l, 16, 0, 0);
}

// Round-0 proven main loop (LDS noise staging + chunk-ahead prefetch, RPW=2)
// + round-1 verified pack-halving reduction (31 shuffles/row vs 156).
// amdgpu_waves_per_eu(4,4) PINS the allocator at the 128-VGPR / 4-waves-per-EU
// point: round 1 showed that leaving the max free lets the allocator chase
// 6 waves/EU (84 VGPRs) and spill the accumulators to scratch (2 GB of
// scratch writes, 18x regression).
__global__ __launch_bounds__(256)
__attribute__((amdgpu_waves_per_eu(4, 4)))
void nce_main(
    const float* __restrict__ input,
    const float* __restrict__ weight,
    const float* __restrict__ bias,
    const float* __restrict__ uni,
    const int* __restrict__ target,
    const int* __restrict__ noise,
    float* __restrict__ out)
{
    __shared__ float4 ldsn[KNOI * (CHUNK / 4)];   // 25 rows x 1KB = 25.6 KB

    float* pmt = out;
    float* pnt = out + NTOK;
    float* pmn = out + 2 * NTOK;
    float* pnn = out + 2 * NTOK + NTOK * KNOI;

    const int lane = threadIdx.x & 63;
    const int wave = threadIdx.x >> 6;
    int row0 = (blockIdx.x * WPB + wave) * RPW;
    row0 = __builtin_amdgcn_readfirstlane(row0);   // wave-uniform -> SGPR

    // Noise byte offsets only (uniform -> SGPRs).
    unsigned noffb[KNOI];
#pragma unroll
    for (int k = 0; k < KNOI; ++k)
        noffb[k] = (unsigned)noise[k] * (unsigned)(HDIM * 4);

    unsigned toffb[RPW], ioffb[RPW];
#pragma unroll
    for (int r = 0; r < RPW; ++r) {
        toffb[r] = (unsigned)target[row0 + r] * (unsigned)(HDIM * 4);
        ioffb[r] = (unsigned)(row0 + r) * (unsigned)(HDIM * 4);
    }

    const char* wb = (const char*)weight;
    const char* ib = (const char*)input;
    const unsigned laneoff = (unsigned)lane * 16u;

    float acc[RPW][KNOI];
    float acct[RPW];
#pragma unroll
    for (int r = 0; r < RPW; ++r) {
        acct[r] = 0.f;
#pragma unroll
        for (int k = 0; k < KNOI; ++k) acc[r][k] = 0.f;
    }

    // Prefetch chunk 0's input/target float4s.
    float4 inv[RPW], tgv[RPW];
#pragma unroll
    for (int r = 0; r < RPW; ++r) {
        inv[r] = *(const float4*)(ib + ioffb[r] + laneoff);
        tgv[r] = *(const float4*)(wb + toffb[r] + laneoff);
    }

    for (int c = 0; c < NCHUNK; ++c) {
        const unsigned cb = (unsigned)c * (unsigned)(CHUNK * 4);

        // Stage noise chunk: wave w loads rows k = j*4+w (one 1KB row-chunk
        // per wave-iteration; wave-uniform branch).
#pragma unroll
        for (int j = 0; j < 7; ++j) {
            const int k = j * WPB + wave;
            if (k < KNOI)
                stage16(wb + noffb[k] + cb + laneoff, &ldsn[k * (CHUNK / 4)]);
        }
        __syncthreads();   // drains staging (vmcnt) + makes LDS visible

        // Snapshot current chunk's in/target, then prefetch next chunk's.
        const float4 in0 = inv[0], in1 = inv[1];
        const float4 tg0 = tgv[0], tg1 = tgv[1];
        const unsigned nb = (unsigned)((c + 1) & (NCHUNK - 1)) * (unsigned)(CHUNK * 4);
#pragma unroll
        for (int r = 0; r < RPW; ++r) {
            inv[r] = *(const float4*)(ib + ioffb[r] + nb + laneoff);
            tgv[r] = *(const float4*)(wb + toffb[r] + nb + laneoff);
        }

#pragma unroll
        for (int k = 0; k < KNOI; ++k) {
            const float4 w = ldsn[k * (CHUNK / 4) + lane];   // ds_read_b128
            acc[0][k] += in0.x * w.x + in0.y * w.y + in0.z * w.z + in0.w * w.w;
            acc[1][k] += in1.x * w.x + in1.y * w.y + in1.z * w.z + in1.w * w.w;
        }
        acct[0] += in0.x * tg0.x + in0.y * tg0.y + in0.z * tg0.z + in0.w * tg0.w;
        acct[1] += in1.x * tg1.x + in1.y * tg1.y + in1.z * tg1.z + in1.w * tg1.w;

        __syncthreads();   // protect LDS before next chunk's staging
    }

    // Pack-halving multi-value wave reduction (verified in round 1): 32 slots
    // (25 noise + target + 6 zero pads) reduced in 5 pairing steps + 1 final
    // butterfly = 31 shuffles/row vs 156 for per-value butterfly. Final:
    // lane L holds total of value m = bits(L5,L4,L3,L2,L1); even lane of
    // each pair stores -> epilogue is lane-parallel, not serialized.
    const int m = ((lane >> 5) & 1) | (((lane >> 4) & 1) << 1)
                | (((lane >> 3) & 1) << 2) | (((lane >> 2) & 1) << 3)
                | (((lane >> 1) & 1) << 4);

#pragma unroll
    for (int r = 0; r < RPW; ++r) {
        float v[32];   // fully unrolled -> stays in registers
#pragma unroll
        for (int k = 0; k < KNOI; ++k) v[k] = acc[r][k];
        v[KNOI] = acct[r];
#pragma unroll
        for (int j = KNOI + 1; j < 32; ++j) v[j] = 0.f;

#pragma unroll
        for (int s = 0; s < 5; ++s) {
            const int h  = 32 >> s;   // lane bit / shfl mask: 32,16,8,4,2
            const int np = 16 >> s;   // pairs this step
#pragma unroll
            for (int i = 0; i < np; ++i) {
                const float lo = v[2 * i], hi = v[2 * i + 1];
                const bool up = (lane & h) != 0;
                const float send = up ? lo : hi;
                const float recv = __shfl_xor(send, h, 64);
                v[i] = (up ? hi : lo) + recv;
            }
        }
        const float tot = v[0] + __shfl_xor(v[0], 1, 64);

        if ((lane & 1) == 0) {
            const int row = row0 + r;
            if (m < KNOI) {
                const int nk = noise[m];                     // L2-hot gathers
                pmn[row * KNOI + m] = expf(tot + bias[nk]);
                pnn[row * KNOI + m] = uni[nk];
            } else if (m == KNOI) {
                const int tk = (int)(toffb[r] >> 13);        // off = idx*8192
                pmt[row] = expf(tot + bias[tk]);
                pnt[row] = uni[tk];
            }
        }
    }
}

extern "C" void kernel_launch(void* const* d_in, const int* in_sizes, int n_in,
                              void* d_out, int out_size, void* d_ws, size_t ws_size,
                              hipStream_t stream) {
    const float* input  = (const float*)d_in[0];
    const float* weight = (const float*)d_in[1];
    const float* bias   = (const float*)d_in[2];
    const float* uni    = (const float*)d_in[3];
    const int*   target = (const int*)d_in[4];
    const int*   noise  = (const int*)d_in[5];
    float* out = (float*)d_out;

    const dim3 grid(NTOK / (WPB * RPW));   // 2048 blocks
    const dim3 block(256);
    hipLaunchKernelGGL(nce_main, grid, block, 0, stream,
                       input, weight, bias, uni, target, noise, out);
}